// Round 12
// baseline (321.883 us; speedup 1.0000x reference)
//
#include <hip/hip_runtime.h>
#include <hip/hip_bf16.h>

// Problem: B=2, S=2048, D_MODEL=1024, H=16, DK=64.
// out = ((l2norm(Q Wq^T) l2norm(K Wk^T)^T)^2 (V Wv^T)) Wo^T   (per head)
// fp32 in/out; internally bf16 MFMA with fp32 accumulation.
//
// Round 20 changes vs round 19:
//  - qkv bank-conflict fix: BK=32 chunk swizzle was quad^(row&3) -> only 2
//    distinct chunks across same-parity rows -> 4-way conflict on every
//    frag ds_read_b128 (3.24M measured). Now quad^((row>>1)&3): consecutive
//    same-parity rows cycle all 4 chunks -> 2-way (free). Source pre-swizzle
//    in loadA/stageW updated to match (involution).
//  - writeA uses v_cvt_pk (pack2bf): 16 scalar cvt -> 8 packed per stage.
//  - attn: staging ring 4 -> 3 bufs (48 KB; 17.4 KB epilogue overlay fits)
//    + launch_bounds(256,3) -> 3 blocks/CU (VGPR 128 <= 170 cap).
//    Ledger: prologue t0..t2 (12 loads); steady WAIT_VM(4); stage t2p+3,
//    t2p+4 into the two just-consumed bufs (2p+3==2p, 2p+4==2p+1 mod 3);
//    tail: p=14 stages only t31, p=15 WAIT_VM(0).

#define D_MODEL 1024
#define N_HEADS 16
#define D_K     64
#define BATCH   2
#define SEQ     2048
#define M_TOT   (BATCH * SEQ)   // 4096

typedef short  s16x8 __attribute__((ext_vector_type(8)));   // 8 bf16 = 4 VGPR
typedef short  s16x4 __attribute__((ext_vector_type(4)));   // 4 bf16 = 2 VGPR
typedef float  f32x4 __attribute__((ext_vector_type(4)));   // MFMA C/D frag
typedef unsigned short ushort_t;
typedef ushort_t us4 __attribute__((ext_vector_type(4)));
typedef ushort_t us8 __attribute__((ext_vector_type(8)));

__device__ __forceinline__ ushort_t f2bf(float f) {
    union { float f; unsigned int u; } x; x.f = f;
    unsigned int u = x.u;
    return (ushort_t)((u + 0x7fffu + ((u >> 16) & 1u)) >> 16);  // RNE
}
__device__ __forceinline__ float bf2f(ushort_t h) {
    union { unsigned int u; float f; } x; x.u = ((unsigned int)h) << 16;
    return x.f;
}
// pack two fp32 -> u32 of two bf16 (RNE)
__device__ __forceinline__ unsigned int pack2bf(float a, float b) {
    union { __hip_bfloat162 h; unsigned int u; } x;
    x.h = __float22bfloat162_rn(float2{a, b});
    return x.u;
}

// async global->LDS, 16B per lane (lane i's lds ptr == wave base + i*16).
__device__ __forceinline__ void gload_lds16(const ushort_t* g, ushort_t* l) {
    __builtin_amdgcn_global_load_lds(
        (__attribute__((address_space(1))) void*)(ushort_t*)g,
        (__attribute__((address_space(3))) void*)l, 16, 0, 0);
}

#define WAIT_VM(n)  asm volatile("s_waitcnt vmcnt(" #n ")" ::: "memory")
#define WAIT_LGKM0  asm volatile("s_waitcnt lgkmcnt(0)" ::: "memory")
#define BARRIER     asm volatile("s_barrier" ::: "memory")

// ---------------------------------------------------------------------------
// fp32 -> bf16 conversion: weights + biases only (8 tensors).
// ---------------------------------------------------------------------------
struct ConvArgs {
    const float* src[8];
    ushort_t*    dst[8];
    int          n[8];
    int          cum[9];   // chunk prefix sums (2048-elem chunks)
};

__global__ __launch_bounds__(256) void convert_kernel(ConvArgs a) {
    const int lin = blockIdx.x;
    int t = 0;
#pragma unroll
    for (int i = 0; i < 8; ++i)
        if (lin >= a.cum[i + 1]) t = i + 1;
    const int off = (lin - a.cum[t]) * 2048 + threadIdx.x * 8;
    if (off >= a.n[t]) return;
    const float4 v0 = *(const float4*)(a.src[t] + off);
    const float4 v1 = *(const float4*)(a.src[t] + off + 4);
    us8 p;
    p[0] = f2bf(v0.x); p[1] = f2bf(v0.y); p[2] = f2bf(v0.z); p[3] = f2bf(v0.w);
    p[4] = f2bf(v1.x); p[5] = f2bf(v1.y); p[6] = f2bf(v1.z); p[7] = f2bf(v1.w);
    *(us8*)(a.dst[t] + off) = p;
}

// ---------------------------------------------------------------------------
// GEMM body BK=64 (used by wo): BM x 128 tile, 4 waves 2x2, 2-deep DMA
// pipeline, issue-early staging. fp32 store.
// ---------------------------------------------------------------------------
template <int BM>
__device__ __forceinline__ void gemm_body(
    ushort_t* __restrict__ smem,
    const ushort_t* __restrict__ A,
    const ushort_t* __restrict__ W,
    const ushort_t* __restrict__ bias,
    float* __restrict__ outf,
    int bx, int by)
{
    static_assert(BM == 64 || BM == 128, "");
    constexpr int K    = 1024;
    constexpr int MF   = BM / 32;
    constexpr int BUFW = (BM + 128) * 64;
    constexpr int NIT  = K / 64;

    const int t    = threadIdx.x;
    const int wave = t >> 6;
    const int lane = t & 63;
    const int quad = lane >> 4;
    const int lc   = lane & 15;
    const int wm   = wave >> 1;
    const int wn   = wave & 1;
    const int m0   = bx * BM;
    const int n0   = by * 128;

    f32x4 acc[MF][4];
    const f32x4 zero = {0.f, 0.f, 0.f, 0.f};
#pragma unroll
    for (int i = 0; i < MF; ++i)
#pragma unroll
        for (int j = 0; j < 4; ++j) acc[i][j] = zero;

    auto stage = [&](int buf, int k0) {
        ushort_t* Ast = smem + buf * BUFW;
        ushort_t* Bst = Ast + BM * 64;
#pragma unroll
        for (int c = 0; c < MF; ++c) {
            int idx = c * 256 + t;
            int row = idx >> 3, phys = idx & 7;
            int col = (phys ^ (row & 7)) * 8;
            gload_lds16(A + (size_t)(m0 + row) * K + k0 + col, Ast + idx * 8);
        }
#pragma unroll
        for (int c = 0; c < 4; ++c) {
            int idx = c * 256 + t;
            int row = idx >> 3, phys = idx & 7;
            int col = (phys ^ (row & 7)) * 8;
            gload_lds16(W + (size_t)(n0 + row) * K + k0 + col, Bst + idx * 8);
        }
    };
    auto loadfrags = [&](int buf, s16x8 (&a)[MF][2], s16x8 (&b)[4][2]) {
        ushort_t* Ast = smem + buf * BUFW;
        ushort_t* Bst = Ast + BM * 64;
#pragma unroll
        for (int ks = 0; ks < 2; ++ks) {
            const int ph = ((ks * 4 + quad) ^ (lc & 7)) * 8;
#pragma unroll
            for (int i = 0; i < MF; ++i)
                a[i][ks] = *(const s16x8*)(Ast + (wm * (BM / 2) + i * 16 + lc) * 64 + ph);
#pragma unroll
            for (int i = 0; i < 4; ++i)
                b[i][ks] = *(const s16x8*)(Bst + (wn * 64 + i * 16 + lc) * 64 + ph);
        }
    };
    auto mfmas = [&](s16x8 (&a)[MF][2], s16x8 (&b)[4][2]) {
#pragma unroll
        for (int ks = 0; ks < 2; ++ks)
#pragma unroll
            for (int mf = 0; mf < MF; ++mf)
#pragma unroll
                for (int nf = 0; nf < 4; ++nf)
                    acc[mf][nf] = __builtin_amdgcn_mfma_f32_16x16x32_bf16(
                        a[mf][ks], b[nf][ks], acc[mf][nf], 0, 0, 0);
    };

    stage(0, 0);
    stage(1, 64);
    s16x8 afr[MF][2], bfr[4][2];
    for (int it = 0; it < NIT; ++it) {
        if (it < NIT - 1) {
            if constexpr (BM == 128) WAIT_VM(8); else WAIT_VM(6);
        } else {
            WAIT_VM(0);
        }
        BARRIER;                       // tile `it` landed
        loadfrags(it & 1, afr, bfr);
        WAIT_LGKM0;
        BARRIER;                       // all waves' reads done -> buf reusable
        if (it < NIT - 2) stage(it & 1, (it + 2) * 64);   // issue-early DMA
        mfmas(afr, bfr);               // covers the DMA flight
    }

    float bv[4];
#pragma unroll
    for (int nf = 0; nf < 4; ++nf) bv[nf] = bf2f(bias[n0 + wn * 64 + nf * 16 + lc]);

#pragma unroll
    for (int mf = 0; mf < MF; ++mf)
#pragma unroll
        for (int nf = 0; nf < 4; ++nf)
#pragma unroll
            for (int r = 0; r < 4; ++r) {
                int mg = m0 + wm * (BM / 2) + mf * 16 + quad * 4 + r;
                int ng = n0 + wn * 64 + nf * 16 + lc;
                outf[(size_t)mg * D_MODEL + ng] = acc[mf][nf][r] + bv[nf];
            }
}

// ---------------------------------------------------------------------------
// Fused GEMM body BK=32 for qkv, fp32 A (conversion in staging).
// LDS: Abuf 2 x 8 KB + Wbuf 3 x 8 KB = 40 KB -> 3 blocks/CU.
// Chunk swizzle: phys chunk p at row r holds logical chunk p ^ ((r>>1)&3)
// (consecutive same-parity rows cycle all 4 chunks -> 2-way reads, free).
// Steady vmcnt ledger at top of iter: [W(it+1):2, A(it+1):4, W(it+2):2].
// MODE 1: L2-norm -> (B,H,S,DK)   MODE 2: transpose -> (B,H,DK,S)
// ---------------------------------------------------------------------------
template <int MODE>
__device__ __forceinline__ void gemm_body32f(
    ushort_t* __restrict__ smem,
    const float* __restrict__ Af,
    const ushort_t* __restrict__ W,
    const ushort_t* __restrict__ bias,
    ushort_t* __restrict__ out,
    int bx, int by)
{
    constexpr int K   = 1024;
    constexpr int NIT = K / 32;            // 32

    const int t    = threadIdx.x;
    const int wave = t >> 6;
    const int lane = t & 63;
    const int quad = lane >> 4;
    const int lc   = lane & 15;
    const int wm   = wave >> 1;
    const int wn   = wave & 1;
    const int m0   = bx * 128;
    const int n0   = by * 128;

    f32x4 acc[4][4];
    const f32x4 zero = {0.f, 0.f, 0.f, 0.f};
#pragma unroll
    for (int i = 0; i < 4; ++i)
#pragma unroll
        for (int j = 0; j < 4; ++j) acc[i][j] = zero;

    float4 ar[4];                          // in-flight fp32 A regs (16 VGPR)
    auto loadA = [&](int k0) {
#pragma unroll
        for (int c = 0; c < 2; ++c) {
            int idx = c * 256 + t;
            int row = idx >> 2, phys = idx & 3;
            int col = (phys ^ ((row >> 1) & 3)) * 8;
            const float* src = Af + (size_t)(m0 + row) * K + k0 + col;
            ar[c * 2]     = *(const float4*)(src);
            ar[c * 2 + 1] = *(const float4*)(src + 4);
        }
    };
    auto writeA = [&](int abuf) {
        ushort_t* Ast = smem + abuf * 4096;
#pragma unroll
        for (int c = 0; c < 2; ++c) {
            int idx = c * 256 + t;
            union { unsigned int u[4]; us8 v; } pk;
            pk.u[0] = pack2bf(ar[c * 2].x, ar[c * 2].y);
            pk.u[1] = pack2bf(ar[c * 2].z, ar[c * 2].w);
            pk.u[2] = pack2bf(ar[c * 2 + 1].x, ar[c * 2 + 1].y);
            pk.u[3] = pack2bf(ar[c * 2 + 1].z, ar[c * 2 + 1].w);
            *(us8*)(Ast + idx * 8) = pk.v;
        }
    };
    auto stageW = [&](int wbuf, int k0) {
        ushort_t* Wst = smem + 8192 + wbuf * 4096;
#pragma unroll
        for (int c = 0; c < 2; ++c) {
            int idx = c * 256 + t;
            int row = idx >> 2, phys = idx & 3;
            int col = (phys ^ ((row >> 1) & 3)) * 8;
            gload_lds16(W + (size_t)(n0 + row) * K + k0 + col, Wst + idx * 8);
        }
    };
    auto loadfrags = [&](int abuf, int wbuf, s16x8 (&a)[4], s16x8 (&b)[4]) {
        ushort_t* Ast = smem + abuf * 4096;
        ushort_t* Wst = smem + 8192 + wbuf * 4096;
#pragma unroll
        for (int i = 0; i < 4; ++i) {
            int ra = wm * 64 + i * 16 + lc;
            a[i] = *(const s16x8*)(Ast + ra * 32 + ((quad ^ ((ra >> 1) & 3)) * 8));
            int rb = wn * 64 + i * 16 + lc;
            b[i] = *(const s16x8*)(Wst + rb * 32 + ((quad ^ ((rb >> 1) & 3)) * 8));
        }
    };
    auto mfmas = [&](s16x8 (&a)[4], s16x8 (&b)[4]) {
#pragma unroll
        for (int mf = 0; mf < 4; ++mf)
#pragma unroll
            for (int nf = 0; nf < 4; ++nf)
                acc[mf][nf] = __builtin_amdgcn_mfma_f32_16x16x32_bf16(
                    a[mf], b[nf], acc[mf][nf], 0, 0, 0);
    };

    // prologue: queue after = [W1:2, A1:4, W2:2]; tile0 ready in LDS.
    loadA(0);                              // A0:4
    stageW(0, 0);                          // W0:2
    stageW(1, 32);                         // W1:2
    WAIT_VM(4);                            // A0 regs landed
    writeA(0);
    loadA(32);                             // A1:4
    stageW(2, 64);                         // W2:2  queue: W0,W1,A1,W2 = 10
    WAIT_VM(8);                            // W0 landed
    WAIT_LGKM0;                            // A0 ds_writes visible
    BARRIER;                               // tile0 ready everywhere

    s16x8 afr[4], bfr[4];
    for (int it = 0; it < NIT; ++it) {
        loadfrags(it & 1, it % 3, afr, bfr);   // ds_read tile it
        if (it < NIT - 1) {
            if (it < NIT - 2) { WAIT_VM(2); }  // drain W(it+1)+A(it+1)
            else              { WAIT_VM(0); }  // tail: only [W,A](NIT-1) left
            writeA((it + 1) & 1);
        }
        WAIT_LGKM0;                        // frag reads + A writes drained
        BARRIER;                           // tile it+1 ready; tile it bufs free
        if (it < NIT - 2) loadA((it + 2) * 32);
        if (it < NIT - 3) stageW((it + 3) % 3, (it + 3) * 32);
        mfmas(afr, bfr);                   // covers the DMA flight
    }

    float bv[4];
#pragma unroll
    for (int nf = 0; nf < 4; ++nf) bv[nf] = bf2f(bias[n0 + wn * 64 + nf * 16 + lc]);

    if (MODE == 1) {
#pragma unroll
        for (int mf = 0; mf < 4; ++mf)
#pragma unroll
            for (int r = 0; r < 4; ++r) {
                float ss = 0.f;
#pragma unroll
                for (int nf = 0; nf < 4; ++nf) {
                    float v = acc[mf][nf][r] + bv[nf];
                    acc[mf][nf][r] = v;
                    ss += v * v;
                }
                ss += __shfl_xor(ss, 1);
                ss += __shfl_xor(ss, 2);
                ss += __shfl_xor(ss, 4);
                ss += __shfl_xor(ss, 8);
                float inv = rsqrtf(ss + 1e-8f);
                int mg = m0 + wm * 64 + mf * 16 + quad * 4 + r;
                int b  = mg >> 11;
                int s  = mg & 2047;
#pragma unroll
                for (int nf = 0; nf < 4; ++nf) {
                    int ng = n0 + wn * 64 + nf * 16 + lc;
                    int h = ng >> 6, d = ng & 63;
                    out[(((size_t)(b * N_HEADS + h)) * SEQ + s) * D_K + d] =
                        f2bf(acc[mf][nf][r] * inv);
                }
            }
    } else {
        __syncthreads();
        ushort_t* vt = smem + wave * (64 * 72);   // 18432 <= 20480 elems
#pragma unroll
        for (int mf = 0; mf < 4; ++mf)
#pragma unroll
            for (int nf = 0; nf < 4; ++nf) {
                us4 p;
#pragma unroll
                for (int r = 0; r < 4; ++r) p[r] = f2bf(acc[mf][nf][r] + bv[nf]);
                *(us4*)(vt + (nf * 16 + lc) * 72 + mf * 16 + quad * 4) = p;
            }
        WAIT_LGKM0;
        __syncthreads();
#pragma unroll
        for (int r = 0; r < 8; ++r) {
            int d  = r * 8 + (lane >> 3);
            int so = (lane & 7) * 8;
            uint4 val = *(const uint4*)(vt + d * 72 + so);
            int mg = m0 + wm * 64 + so;
            int b  = mg >> 11;
            int s  = mg & 2047;
            int ng = n0 + wn * 64 + d;
            int h = ng >> 6, dh = ng & 63;
            *(uint4*)(out + (((size_t)(b * N_HEADS + h)) * D_K + dh) * SEQ + s) = val;
        }
    }
}

// qkv: 1-D grid 768 = 256 CU x 3, single round. XCD mapping: xcd = lin&7
// owns 12 contiguous (z,bx) A-tiles; its 8 by-blocks share each A-tile
// in its L2 -> fp32 A fetched from HBM once.
__global__ __launch_bounds__(256, 3) void qkv_kernel(
    const float* __restrict__ Qf, const float* __restrict__ Kf,
    const float* __restrict__ Vf,
    const ushort_t* __restrict__ Wq, const ushort_t* __restrict__ Wk,
    const ushort_t* __restrict__ Wv,
    const ushort_t* __restrict__ bq, const ushort_t* __restrict__ bk,
    const ushort_t* __restrict__ bv,
    ushort_t* __restrict__ qn, ushort_t* __restrict__ kn,
    ushort_t* __restrict__ vT)
{
    __shared__ __align__(16) ushort_t smem[20480];   // 40 KB
    const int lin = blockIdx.x;
    const int xcd = lin & 7;
    const int idx = lin >> 3;          // 0..95
    const int zbx = xcd * 12 + (idx % 12);   // 0..95, contiguous per XCD
    const int by  = idx / 12;          // 0..7
    const int z   = zbx >> 5;          // 0..2
    const int bx  = zbx & 31;
    if (z == 0)
        gemm_body32f<1>(smem, Qf, Wq, bq, qn, bx, by);
    else if (z == 1)
        gemm_body32f<1>(smem, Kf, Wk, bk, kn, bx, by);
    else
        gemm_body32f<2>(smem, Vf, Wv, bv, vT, bx, by);
}

// wo: 1-D grid 512; lin%8 = N-panel; BM=64 BK=64 (48 KB LDS).
__global__ __launch_bounds__(256) void wo_kernel(
    const ushort_t* __restrict__ A, const ushort_t* __restrict__ W,
    const ushort_t* __restrict__ bias, float* __restrict__ outf)
{
    __shared__ __align__(16) ushort_t smem[2 * (64 + 128) * 64];   // 48 KB
    const int lin = blockIdx.x;
    gemm_body<64>(smem, A, W, bias, outf, lin >> 3, lin & 7);
}

// ---------------------------------------------------------------------------
// Attention: per (b,h): out = (qn kn^T)^2 v.
// Grid (x=bh 32, y=qt 16) -> 512 blocks; bh%8 XCD pin. 128 q/block.
// Tile PAIRS with K=32 PV (squared S^T D-frags packed as B-frag).
// R20: 3-buf ring (48 KB) -> 3 blocks/CU; steady WAIT_VM(4).
// ---------------------------------------------------------------------------
__global__ __launch_bounds__(256, 3) void attn_kernel(
    const ushort_t* __restrict__ qn,
    const ushort_t* __restrict__ kn,
    const ushort_t* __restrict__ vT,
    ushort_t* __restrict__ attn_out)
{
    // staging buf i at smem+i*8192: kst [64 j][64 dk] + vst [64 d][64 j]
    // (both 8-el-chunk XOR-swizzled). Epilogue overlays f32 red buf (17.4 KB).
    __shared__ __align__(16) ushort_t smem[3 * 8192];   // 48 KB

    const int t    = threadIdx.x;
    const int wave = t >> 6;
    const int lane = t & 63;
    const int quad = lane >> 4;
    const int lc   = lane & 15;
    const int bh   = blockIdx.x;       // 0..31 (bh%8 -> XCD pin)
    const int qt   = blockIdx.y;       // 0..15
    const int b    = bh >> 4;
    const int h    = bh & 15;

    const ushort_t* qb = qn + (size_t)bh * SEQ * D_K;
    const ushort_t* kb = kn + (size_t)bh * SEQ * D_K;
    const ushort_t* vb = vT + (size_t)bh * D_K * SEQ;
    const int q0 = qt * 128;

    s16x8 qf[8][2];
#pragma unroll
    for (int mf = 0; mf < 8; ++mf)
#pragma unroll
        for (int ks = 0; ks < 2; ++ks)
            qf[mf][ks] = *(const s16x8*)(qb + (size_t)(q0 + mf * 16 + lc) * D_K +
                                         ks * 32 + quad * 8);

    f32x4 oacc[4][8];
    const f32x4 zero = {0.f, 0.f, 0.f, 0.f};
#pragma unroll
    for (int df = 0; df < 4; ++df)
#pragma unroll
        for (int mf = 0; mf < 8; ++mf) oacc[df][mf] = zero;

    auto stage = [&](int buf, int j0) {
        ushort_t* kst = smem + buf * 8192;
        ushort_t* vst = kst + 4096;
#pragma unroll
        for (int c = 0; c < 2; ++c) {
            int idx = c * 256 + t;
            int row = idx >> 3, phys = idx & 7;
            int col = (phys ^ (row & 7)) * 8;
            gload_lds16(kb + (size_t)(j0 + row) * D_K + col, kst + idx * 8);
            gload_lds16(vb + (size_t)row * SEQ + j0 + col, vst + idx * 8);
        }
    };

    auto compute2 = [&](int ba, int bb) {
        ushort_t* kstA = smem + ba * 8192;
        ushort_t* vstA = kstA + 4096;
        ushort_t* kstB = smem + bb * 8192;
        ushort_t* vstB = kstB + 4096;
        s16x8 akA[2], akB[2];
#pragma unroll
        for (int ks = 0; ks < 2; ++ks) {
            const int off = (wave * 16 + lc) * 64 + (((ks * 4 + quad) ^ (lc & 7)) * 8);
            akA[ks] = *(const s16x8*)(kstA + off);
            akB[ks] = *(const s16x8*)(kstB + off);
        }
        s16x8 av[4];
#pragma unroll
        for (int df = 0; df < 4; ++df) {
            const int d  = df * 16 + lc;
            const int cj = wave * 2 + (quad >> 1);        // logical 8-el chunk
            const int o  = d * 64 + ((cj ^ (d & 7)) << 3) + ((quad & 1) << 2);
            s16x4 lo = *(const s16x4*)(vstA + o);
            s16x4 hi = *(const s16x4*)(vstB + o);
            av[df] = s16x8{lo[0], lo[1], lo[2], lo[3], hi[0], hi[1], hi[2], hi[3]};
        }
#pragma unroll
        for (int mf = 0; mf < 8; ++mf) {
            f32x4 stA = zero, stB = zero;   // S^T: lane = [j=quad*4+r][q=lc]
#pragma unroll
            for (int ks = 0; ks < 2; ++ks) {
                stA = __builtin_amdgcn_mfma_f32_16x16x32_bf16(akA[ks], qf[mf][ks],
                                                              stA, 0, 0, 0);
                stB = __builtin_amdgcn_mfma_f32_16x16x32_bf16(akB[ks], qf[mf][ks],
                                                              stB, 0, 0, 0);
            }
            union { unsigned int u[4]; s16x8 v; } pb;
            pb.u[0] = pack2bf(stA[0] * stA[0], stA[1] * stA[1]);
            pb.u[1] = pack2bf(stA[2] * stA[2], stA[3] * stA[3]);
            pb.u[2] = pack2bf(stB[0] * stB[0], stB[1] * stB[1]);
            pb.u[3] = pack2bf(stB[2] * stB[2], stB[3] * stB[3]);
#pragma unroll
            for (int df = 0; df < 4; ++df)
                oacc[df][mf] = __builtin_amdgcn_mfma_f32_16x16x32_bf16(
                    av[df], pb.v, oacc[df][mf], 0, 0, 0);
        }
    };

    constexpr int NT = 32;
    constexpr int NP = 16;                 // 32 tiles / 2
    stage(0, 0);
    stage(1, 64);
    stage(2, 128);
    for (int p = 0; p < NP; ++p) {
        if (p < NP - 1) { WAIT_VM(4); } else { WAIT_VM(0); }
        BARRIER;                       // tiles 2p,2p+1 landed everywhere
        compute2((2 * p) % 3, (2 * p + 1) % 3);
        if (p < NP - 1) {
            WAIT_LGKM0;
            BARRIER;                   // all reads of this pair's bufs done
            if (2 * p + 3 < NT) stage((2 * p + 3) % 3, (2 * p + 3) * 64);
            if (2 * p + 4 < NT) stage((2 * p + 4) % 3, (2 * p + 4) * 64);
        }
    }

    float* red = (float*)smem;
    constexpr int RP = 17;
#pragma unroll
    for (int mf = 0; mf < 8; ++mf) {
        BARRIER;                       // previous chunk's reads (or loop) done
#pragma unroll
        for (int df = 0; df < 4; ++df)
#pragma unroll
            for (int r = 0; r < 4; ++r)
                red[(wave * 64 + df * 16 + quad * 4 + r) * RP + lc] =
                    oacc[df][mf][r];
        WAIT_LGKM0;
        BARRIER;                       // all partials visible
#pragma unroll
        for (int qq = 0; qq < 4; ++qq) {
            const int q = wave * 4 + qq;
            const int d = lane;
            float v = red[(0 * 64 + d) * RP + q] + red[(1 * 64 + d) * RP + q] +
                      red[(2 * 64 + d) * RP + q] + red[(3 * 64 + d) * RP + q];
            const int s = q0 + mf * 16 + q;
            attn_out[((size_t)(b * SEQ + s)) * D_MODEL + h * D_K + d] = f2bf(v);
        }
    }
}

extern "C" void kernel_launch(void* const* d_in, const int* in_sizes, int n_in,
                              void* d_out, int out_size, void* d_ws, size_t ws_size,
                              hipStream_t stream)
{
    const float* Qf   = (const float*)d_in[0];
    const float* Kf   = (const float*)d_in[1];
    const float* Vf   = (const float*)d_in[2];
    const float* Wqf  = (const float*)d_in[3];
    const float* Wqbf = (const float*)d_in[4];
    const float* Wkf  = (const float*)d_in[5];
    const float* Wkbf = (const float*)d_in[6];
    const float* Wvf  = (const float*)d_in[7];
    const float* Wvbf = (const float*)d_in[8];
    const float* Wof  = (const float*)d_in[9];
    const float* Wobf = (const float*)d_in[10];

    const size_t NM = (size_t)M_TOT * D_MODEL;
    const size_t NW = (size_t)D_MODEL * D_MODEL;
    const size_t NB = D_MODEL;

    ushort_t* p = (ushort_t*)d_ws;
    ushort_t* Wq  = p;  p += NW;
    ushort_t* Wk  = p;  p += NW;
    ushort_t* Wv  = p;  p += NW;
    ushort_t* Wo  = p;  p += NW;
    ushort_t* bq  = p;  p += NB;
    ushort_t* bk  = p;  p += NB;
    ushort_t* bvv = p;  p += NB;
    ushort_t* bo  = p;  p += NB;
    ushort_t* qn  = p;  p += NM;   // (B,H,S,DK)
    ushort_t* kn  = p;  p += NM;   // (B,H,S,DK)
    ushort_t* vT  = p;  p += NM;   // (B,H,DK,S)
    ushort_t* ao  = p;  p += NM;   // (B,S,D)

    ConvArgs ca;
    ca.src[0] = Wqf;  ca.dst[0] = Wq;  ca.n[0] = (int)NW;
    ca.src[1] = Wkf;  ca.dst[1] = Wk;  ca.n[1] = (int)NW;
    ca.src[2] = Wvf;  ca.dst[2] = Wv;  ca.n[2] = (int)NW;
    ca.src[3] = Wof;  ca.dst[3] = Wo;  ca.n[3] = (int)NW;
    ca.src[4] = Wqbf; ca.dst[4] = bq;  ca.n[4] = (int)NB;
    ca.src[5] = Wkbf; ca.dst[5] = bk;  ca.n[5] = (int)NB;
    ca.src[6] = Wvbf; ca.dst[6] = bvv; ca.n[6] = (int)NB;
    ca.src[7] = Wobf; ca.dst[7] = bo;  ca.n[7] = (int)NB;

    int cum = 0;
    ca.cum[0] = 0;
    for (int i = 0; i < 8; ++i) {
        cum += (ca.n[i] + 2047) / 2048;
        ca.cum[i + 1] = cum;
    }

    dim3 blk(256);
    convert_kernel<<<dim3((unsigned)cum), blk, 0, stream>>>(ca);

    qkv_kernel<<<dim3(768), blk, 0, stream>>>(
        Qf, Kf, Vf, Wq, Wk, Wv, bq, bk, bvv, qn, kn, vT);
    attn_kernel<<<dim3(BATCH * N_HEADS, SEQ / 128), blk, 0, stream>>>(qn, kn, vT, ao);
    wo_kernel<<<dim3(512), blk, 0, stream>>>(
        ao, Wo, bo, (float*)d_out);
}